// Round 3
// baseline (491.099 us; speedup 1.0000x reference)
//
#include <hip/hip_runtime.h>

#define NN     200000
#define MPAD   200064   // 1563 * 128
#define NGRAPH 1024

typedef __bf16 bf16x8 __attribute__((ext_vector_type(8)));
typedef float  f32x4  __attribute__((ext_vector_type(4)));
typedef float  f32x2  __attribute__((ext_vector_type(2)));

// ---------- helpers ----------
__device__ __forceinline__ unsigned short f2bu(float f) {
    unsigned u = __float_as_uint(f);
    unsigned r = (u + 0x7FFFu + ((u >> 16) & 1u)) >> 16;
    return (unsigned short)r;
}
__device__ __forceinline__ float b2f(unsigned short u) {
    return __uint_as_float(((unsigned)u) << 16);
}
__device__ __forceinline__ unsigned cvt_pk(float lo, float hi) {
    // RNE, bit-identical to f2bu for finite inputs
    unsigned r;
    asm("v_cvt_pk_bf16_f32 %0, %1, %2" : "=v"(r) : "v"(lo), "v"(hi));
    return r;
}

// ---------- kernel 1: weight prep ----------
// wcatT[n][k] = [Wg1|Wn1][k][n] bf16.
// wfragT: 8 slices x 64 lanes x 8 bf16 — B-fragments for the fused alpha
// MFMA. Slice s = ct*4 + wn*2 + p; element e of lane l holds
// Wg2x[n(s,quad,e)][c] where n = ct*128+wn*64+p*32+(e>>2)*16+quad*4+(e&3),
// c = l&15: c<8 -> bf16 hi of Wg2[n][c]; c>=8 -> bf16 residual (lo) of
// Wg2[n][c-8]  (hi+lo summed later == fp32-accurate Wg2).
__global__ __launch_bounds__(256) void convert_w(
    const float* __restrict__ Wg1, const float* __restrict__ Wn1,
    const float* __restrict__ Wg2,
    unsigned short* __restrict__ wcatT, unsigned short* __restrict__ wfragT) {
    int i = blockIdx.x * 256 + threadIdx.x;
    if (i < 512 * 256) {
        int n = i >> 8, k = i & 255;
        float v = (n < 256) ? Wg1[k * 256 + n] : Wn1[k * 256 + (n - 256)];
        wcatT[i] = f2bu(v);
    } else if (i < 512 * 256 + 4096) {
        int j = i - 512 * 256;
        int e = j & 7, l = (j >> 3) & 63, s = j >> 9;
        int quad = l >> 4, c = l & 15;
        int n = (s >> 2) * 128 + ((s >> 1) & 1) * 64 + (s & 1) * 32
              + ((e >> 2) * 16) + quad * 4 + (e & 3);
        float w = Wg2[n * 8 + (c & 7)];
        unsigned short hi = f2bu(w);
        wfragT[j] = (c < 8) ? hi : f2bu(w - b2f(hi));
    }
}

// ---------- kernel 2: fused GEMM + alpha ----------
// h_n = relu(x@Wn1 + bn1)  -> C [MPAD,256] bf16   (col-tiles ct=2,3)
// alpha = relu(x@Wg1)@Wg2  -> alpha [NN,8] f32    (col-tiles ct=0,1, fused)
// MFMA operands SWAPPED: mfma(bf, af, acc) puts the output row on lane&15
// and 4 consecutive output cols on the reg axis.
// B (wcatT, 256 KB) is L2-resident: B-fragments are read DIRECTLY from
// global into registers (16B aligned) — no Bs LDS, and therefore NO
// barriers in the K-loop (round-2 bottleneck: per-kc global_load_lds +
// vmcnt(0) barrier drain -> MfmaUtil 12%). Only one barrier after A-stage.
__global__ __launch_bounds__(256, 2) void gemm_fused(
    const float* __restrict__ x,              // [NN,256] f32
    const unsigned short* __restrict__ Bt,    // wcatT [512,256] bf16
    const float* __restrict__ bn1,            // [256]
    const unsigned short* __restrict__ wfragT,// [8*64*8] bf16
    unsigned short* __restrict__ C,           // h_n [MPAD,256] bf16
    float* __restrict__ alpha) {              // [NN,8] f32
    __shared__ unsigned short As[128 * 256];  // 64 KB
    __shared__ float redA[128 * 8];           // 4 KB (alpha cross-wave red)
    const int tid  = threadIdx.x;
    const int lane = tid & 63;
    const int wave = tid >> 6;
    const int wm = wave >> 1, wn = wave & 1;
    const size_t m0 = (size_t)blockIdx.x * 128;
    const int frow = lane & 15;
    const int quad = lane >> 4;

    // ---- stage A panel: f32 x -> bf16, swizzled chunk c -> slot c^(r&7).
    // row = p*4 + wave; col = lane*4 (16B/lane coalesced). 8 loads batched
    // per pass for memory-level parallelism.
    {
        const int lane4 = lane * 4;
        const int c = lane4 >> 3;
        #pragma unroll 1
        for (int p4 = 0; p4 < 4; ++p4) {
            float4 v[8];
            #pragma unroll
            for (int q = 0; q < 8; ++q) {
                int row = (p4 * 8 + q) * 4 + wave;
                size_t gr = m0 + row;
                if (gr > (size_t)(NN - 1)) gr = NN - 1;   // clamp pad rows
                v[q] = *(const float4*)(x + gr * 256 + lane4);
            }
            #pragma unroll
            for (int q = 0; q < 8; ++q) {
                int row = (p4 * 8 + q) * 4 + wave;
                unsigned u0 = cvt_pk(v[q].x, v[q].y);
                unsigned u1 = cvt_pk(v[q].z, v[q].w);
                int off = row * 256 + ((c ^ (row & 7)) << 3) + (lane4 & 7);
                uint2 w; w.x = u0; w.y = u1;
                *(uint2*)(As + off) = w;          // 8B, aligned
            }
        }
    }
    __syncthreads();

    f32x4 aacc[4] = {};   // alpha accumulator (persists over ct=0,1)

    #pragma unroll 1
    for (int ct = 0; ct < 4; ++ct) {
        const int n0 = ct * 128;
        f32x4 acc[4][4] = {};
        #pragma unroll
        for (int kc = 0; kc < 4; ++kc) {
            #pragma unroll
            for (int kk = 0; kk < 2; ++kk) {
                const int sa = (kc * 8 + kk * 4 + quad) ^ (frow & 7);
                const int kb = kc * 64 + (kk * 4 + quad) * 8;
                bf16x8 af[4], bf[4];
                #pragma unroll
                for (int j = 0; j < 4; ++j)
                    bf[j] = *(const bf16x8*)(
                        Bt + (size_t)(n0 + wn * 64 + j * 16 + frow) * 256 + kb);
                #pragma unroll
                for (int i = 0; i < 4; ++i)
                    af[i] = *(const bf16x8*)(As + (wm * 64 + i * 16 + frow) * 256 + sa * 8);
                #pragma unroll
                for (int i = 0; i < 4; ++i)
                    #pragma unroll
                    for (int j = 0; j < 4; ++j)
                        acc[i][j] = __builtin_amdgcn_mfma_f32_16x16x32_bf16(
                            bf[j], af[i], acc[i][j], 0, 0, 0);   // SWAPPED
            }
        }

        if (ct < 2) {
            // ---- fused alpha: relu(acc) is an A-fragment (row=frow=node,
            // k-slot(quad,e)=col per wfragT's permutation); 2 j-pairs -> K=32.
            #pragma unroll
            for (int p = 0; p < 2; ++p) {
                bf16x8 wf = *(const bf16x8*)(
                    wfragT + (((ct << 2) + (wn << 1) + p) * 64 + lane) * 8);
                #pragma unroll
                for (int i = 0; i < 4; ++i) {
                    f32x4 v0 = acc[i][2 * p], v1 = acc[i][2 * p + 1];
                    unsigned u0 = cvt_pk(fmaxf(v0[0], 0.f), fmaxf(v0[1], 0.f));
                    unsigned u1 = cvt_pk(fmaxf(v0[2], 0.f), fmaxf(v0[3], 0.f));
                    unsigned u2 = cvt_pk(fmaxf(v1[0], 0.f), fmaxf(v1[1], 0.f));
                    unsigned u3 = cvt_pk(fmaxf(v1[2], 0.f), fmaxf(v1[3], 0.f));
                    union { unsigned u[4]; bf16x8 b; } a8 = {{u0, u1, u2, u3}};
                    aacc[i] = __builtin_amdgcn_mfma_f32_16x16x32_bf16(
                        a8.b, wf, aacc[i], 0, 0, 0);
                }
            }
            if (ct == 1) {
                // finalize alpha: fold hi+lo residual, reduce across wn
                // halves through redA, write global.
                #pragma unroll
                for (int i = 0; i < 4; ++i)
                    #pragma unroll
                    for (int r = 0; r < 4; ++r)
                        aacc[i][r] += __shfl_xor(aacc[i][r], 8);
                if (wn == 0 && frow < 8) {
                    #pragma unroll
                    for (int i = 0; i < 4; ++i)
                        #pragma unroll
                        for (int r = 0; r < 4; ++r)
                            redA[(wm * 64 + i * 16 + quad * 4 + r) * 8 + frow] = aacc[i][r];
                }
                __syncthreads();
                if (wn == 1 && frow < 8) {
                    #pragma unroll
                    for (int i = 0; i < 4; ++i)
                        #pragma unroll
                        for (int r = 0; r < 4; ++r) {
                            int ml = wm * 64 + i * 16 + quad * 4 + r;
                            size_t m = m0 + ml;
                            if (m < NN)
                                alpha[m * 8 + frow] = redA[ml * 8 + frow] + aacc[i][r];
                        }
                }
            }
        } else {
            // ---- h_n epilogue: bias (vector add along reg axis), relu,
            // pack 4 bf16 -> one 8B store per (i,j).
            #pragma unroll
            for (int j = 0; j < 4; ++j) {
                f32x4 bv = *(const f32x4*)(bn1 + (ct - 2) * 128 + wn * 64 + j * 16 + quad * 4);
                #pragma unroll
                for (int i = 0; i < 4; ++i) {
                    f32x4 v = acc[i][j] + bv;
                    unsigned u0 = cvt_pk(fmaxf(v[0], 0.f), fmaxf(v[1], 0.f));
                    unsigned u1 = cvt_pk(fmaxf(v[2], 0.f), fmaxf(v[3], 0.f));
                    uint2 w; w.x = u0; w.y = u1;
                    size_t row = m0 + wm * 64 + i * 16 + frow;
                    *(uint2*)(C + row * 256 + (ct - 2) * 128 + wn * 64 + j * 16 + quad * 4) = w;
                }
            }
        }
    }
}

// ---------- kernel 3: softmax + gated segment-sum + tiny GEMV ----------
__device__ __forceinline__ int lower_bound(const int* __restrict__ b, int key) {
    int lo = 0, hi = NN;
    while (lo < hi) { int mid = (lo + hi) >> 1; if (b[mid] < key) lo = mid + 1; else hi = mid; }
    return lo;
}

__global__ __launch_bounds__(256) void pool2(
    const float* __restrict__ alpha, const unsigned short* __restrict__ h,
    const float* __restrict__ Wn2, const float* __restrict__ bn2,
    const int* __restrict__ batch, float* __restrict__ out) {
    __shared__ float red[256];
    __shared__ float mh[8], ih[8];
    __shared__ float gate_s[64][8];   // 2 KB
    __shared__ float Gs[256 * 8];     // 8 KB
    const int g = blockIdx.x, t = threadIdx.x;
    const int start = lower_bound(batch, g);
    const int end   = lower_bound(batch, g + 1);
    const int hd = t & 7;

    float mloc = -INFINITY;
    for (int n = start + (t >> 3); n < end; n += 32)
        mloc = fmaxf(mloc, alpha[n * 8 + hd]);
    red[t] = mloc; __syncthreads();
    for (int off = 128; off >= 8; off >>= 1) {
        if (t < off) red[t] = fmaxf(red[t], red[t + off]);
        __syncthreads();
    }
    if (t < 8) mh[t] = red[t];
    __syncthreads();
    const float mm = mh[hd];

    float sloc = 0.f;
    for (int n = start + (t >> 3); n < end; n += 32)
        sloc += __expf(alpha[n * 8 + hd] - mm);
    red[t] = sloc; __syncthreads();
    for (int off = 128; off >= 8; off >>= 1) {
        if (t < off) red[t] += red[t + off];
        __syncthreads();
    }
    if (t < 8) ih[t] = 1.0f / (red[t] + 1e-16f);
    __syncthreads();

    // pass 3: G[k, 0..7] += gate[n,:] * h_n[n, k]
    // 2 node-groups of 128 threads; each thread owns cols {2tc, 2tc+1}
    // via one 4B ushort2 load per node (2x node ILP, half the load instrs).
    const int half = t >> 7;          // node group
    const int tc   = t & 127;         // column-pair index
    f32x2 a0[4] = {}, a1[4] = {};     // col 2tc / 2tc+1, head pairs
    for (int c0 = start; c0 < end; c0 += 64) {
        const int cn = min(64, end - c0);
        __syncthreads();
        for (int u = t; u < cn * 8; u += 256)
            gate_s[u >> 3][u & 7] =
                __expf(alpha[(c0 + (u >> 3)) * 8 + (u & 7)] - mh[u & 7]) * ih[u & 7];
        __syncthreads();
        const int jend = half ? cn : min(cn, 32);
        for (int j = half * 32; j < jend; ++j) {
            unsigned hv = *(const unsigned*)(h + (size_t)(c0 + j) * 256 + tc * 2);
            float h0 = b2f((unsigned short)(hv & 0xFFFFu));
            float h1 = b2f((unsigned short)(hv >> 16));
            f32x2 h20 = {h0, h0}, h21 = {h1, h1};
            const f32x2* gp = (const f32x2*)&gate_s[j][0];   // LDS broadcast
            #pragma unroll
            for (int i = 0; i < 4; ++i) {
                f32x2 g2 = gp[i];
                a0[i] += g2 * h20;
                a1[i] += g2 * h21;
            }
        }
    }
    __syncthreads();
    if (half == 0) {
        #pragma unroll
        for (int i = 0; i < 4; ++i) {
            *(f32x2*)&Gs[(2 * tc) * 8 + 2 * i]     = a0[i];
            *(f32x2*)&Gs[(2 * tc + 1) * 8 + 2 * i] = a1[i];
        }
    }
    __syncthreads();
    if (half == 1) {
        #pragma unroll
        for (int i = 0; i < 4; ++i) {
            *(f32x2*)&Gs[(2 * tc) * 8 + 2 * i]     += a0[i];
            *(f32x2*)&Gs[(2 * tc + 1) * 8 + 2 * i] += a1[i];
        }
    }
    __syncthreads();

    float acc = 0.f;
    #pragma unroll 4
    for (int k = 0; k < 256; ++k)
        acc += Gs[k * 8 + hd] * Wn2[k * 256 + t];
    const float sg = (end > start) ? 1.0f : 0.0f;
    out[g * 256 + t] = acc + sg * bn2[t];
}

// ---------- launch ----------
extern "C" void kernel_launch(void* const* d_in, const int* in_sizes, int n_in,
                              void* d_out, int out_size, void* d_ws, size_t ws_size,
                              hipStream_t stream) {
    const float* x     = (const float*)d_in[0];
    const int*   batch = (const int*)d_in[1];
    const float* Wg1   = (const float*)d_in[2];
    const float* Wg2   = (const float*)d_in[3];
    const float* Wn1   = (const float*)d_in[4];
    const float* bn1   = (const float*)d_in[5];
    const float* Wn2   = (const float*)d_in[6];
    const float* bn2   = (const float*)d_in[7];
    float* out = (float*)d_out;

    unsigned short* h      = (unsigned short*)d_ws;           // MPAD*256 (h_n only)
    unsigned short* wcatT  = h + (size_t)MPAD * 256;          // 512*256
    unsigned short* wfragT = wcatT + 512 * 256;               // 8*64*8
    float* alpha = (float*)(wfragT + 4096);                   // NN*8

    convert_w<<<528, 256, 0, stream>>>(Wg1, Wn1, Wg2, wcatT, wfragT);
    gemm_fused<<<1563, 256, 0, stream>>>(x, wcatT, bn1, wfragT, h, alpha);
    pool2<<<NGRAPH, 256, 0, stream>>>(alpha, h, Wn2, bn2, batch, out);
}

// Round 4
// 438.737 us; speedup vs baseline: 1.1193x; 1.1193x over previous
//
#include <hip/hip_runtime.h>

#define NN     200000
#define MPAD   200064   // 3126 * 64
#define NGRAPH 1024

typedef __bf16 bf16x8 __attribute__((ext_vector_type(8)));
typedef float  f32x4  __attribute__((ext_vector_type(4)));
typedef float  f32x2  __attribute__((ext_vector_type(2)));

// ---------- helpers ----------
__device__ __forceinline__ unsigned short f2bu(float f) {
    unsigned u = __float_as_uint(f);
    unsigned r = (u + 0x7FFFu + ((u >> 16) & 1u)) >> 16;
    return (unsigned short)r;
}
__device__ __forceinline__ float b2f(unsigned short u) {
    return __uint_as_float(((unsigned)u) << 16);
}
__device__ __forceinline__ unsigned cvt_pk(float lo, float hi) {
    // RNE, bit-identical to f2bu for finite inputs
    unsigned r;
    asm("v_cvt_pk_bf16_f32 %0, %1, %2" : "=v"(r) : "v"(lo), "v"(hi));
    return r;
}
__device__ __forceinline__ void async16(const void* g, void* l) {
    __builtin_amdgcn_global_load_lds(
        (const __attribute__((address_space(1))) void*)g,
        (__attribute__((address_space(3))) void*)l, 16, 0, 0);
}

// ---------- kernel 1: weight prep ----------
// wcatT[n][k] = [Wg1|Wn1][k][n] bf16.
// wfragT: 8 slices x 64 lanes x 8 bf16 — B-fragments for the fused alpha
// MFMA. Slice s = ct*4 + wn*2 + p; element e of lane l holds
// Wg2x[n(s,quad,e)][c] where n = ct*128+wn*64+p*32+(e>>2)*16+quad*4+(e&3),
// c = l&15: c<8 -> bf16 hi of Wg2[n][c]; c>=8 -> bf16 residual (lo) of
// Wg2[n][c-8]  (hi+lo summed later == fp32-accurate Wg2).
__global__ __launch_bounds__(256) void convert_w(
    const float* __restrict__ Wg1, const float* __restrict__ Wn1,
    const float* __restrict__ Wg2,
    unsigned short* __restrict__ wcatT, unsigned short* __restrict__ wfragT) {
    int i = blockIdx.x * 256 + threadIdx.x;
    if (i < 512 * 256) {
        int n = i >> 8, k = i & 255;
        float v = (n < 256) ? Wg1[k * 256 + n] : Wn1[k * 256 + (n - 256)];
        wcatT[i] = f2bu(v);
    } else if (i < 512 * 256 + 4096) {
        int j = i - 512 * 256;
        int e = j & 7, l = (j >> 3) & 63, s = j >> 9;
        int quad = l >> 4, c = l & 15;
        int n = (s >> 2) * 128 + ((s >> 1) & 1) * 64 + (s & 1) * 32
              + ((e >> 2) * 16) + quad * 4 + (e & 3);
        float w = Wg2[n * 8 + (c & 7)];
        unsigned short hi = f2bu(w);
        wfragT[j] = (c < 8) ? hi : f2bu(w - b2f(hi));
    }
}

// ---------- kernel 2: fused GEMM + alpha ----------
// M-tile = 64 rows (round-4 change): LDS = As 32K + Bs 16K + redA 2K =
// 50 KB -> 3 blocks/CU (12 waves/CU) vs 2 with the 128-row tile. The
// structure is round-2's best-measured one: B staged via global_load_lds
// + barriers (direct-from-L2 B regressed at 2 waves/SIMD: latency per kk
// exposed, round 3). Swapped MFMA operands: mfma(bf, af, acc) puts output
// row on lane&15, 4 consecutive cols on reg axis -> packed 8B stores,
// vector bias add, and relu(h_g) in regs is directly an A-fragment for
// the fused alpha MFMA (h_g never written; alpha written here).
__global__ __launch_bounds__(256, 3) void gemm_fused(
    const float* __restrict__ x,              // [NN,256] f32
    const unsigned short* __restrict__ Bt,    // wcatT [512,256] bf16
    const float* __restrict__ bn1,            // [256]
    const unsigned short* __restrict__ wfragT,// [8*64*8] bf16
    unsigned short* __restrict__ C,           // h_n [MPAD,256] bf16
    float* __restrict__ alpha) {              // [NN,8] f32
    __shared__ unsigned short As[64 * 256];   // 32 KB
    __shared__ unsigned short Bs[128 * 64];   // 16 KB
    __shared__ float redA[64 * 8];            // 2 KB (alpha cross-wave red)
    const int tid  = threadIdx.x;
    const int lane = tid & 63;
    const int wave = tid >> 6;
    const int wm = wave >> 1, wn = wave & 1;
    const size_t m0 = (size_t)blockIdx.x * 64;
    const int frow = lane & 15;
    const int quad = lane >> 4;

    // ---- stage A panel (64 rows): f32 x -> bf16, swizzled chunk c ->
    // slot c^(r&7). row = p*4 + wave; col = lane*4 (16B/lane coalesced).
    // 8 loads batched per pass for memory-level parallelism.
    {
        const int lane4 = lane * 4;
        const int c = lane4 >> 3;
        #pragma unroll 1
        for (int p2 = 0; p2 < 2; ++p2) {
            float4 v[8];
            #pragma unroll
            for (int q = 0; q < 8; ++q) {
                int row = (p2 * 8 + q) * 4 + wave;
                size_t gr = m0 + row;
                if (gr > (size_t)(NN - 1)) gr = NN - 1;   // clamp pad rows
                v[q] = *(const float4*)(x + gr * 256 + lane4);
            }
            #pragma unroll
            for (int q = 0; q < 8; ++q) {
                int row = (p2 * 8 + q) * 4 + wave;
                unsigned u0 = cvt_pk(v[q].x, v[q].y);
                unsigned u1 = cvt_pk(v[q].z, v[q].w);
                int off = row * 256 + ((c ^ (row & 7)) << 3) + (lane4 & 7);
                uint2 w; w.x = u0; w.y = u1;
                *(uint2*)(As + off) = w;          // 8B, aligned
            }
        }
    }

    // B staging pattern (per col-tile ct, k-chunk kc)
    const int schunk = lane & 7;
    const int srow0  = wave * 32 + (lane >> 3);
    const int swb    = (schunk ^ (srow0 & 7)) * 8;
    unsigned short* lB = Bs + wave * 2048;

    f32x4 aacc[2] = {};   // alpha accumulator (persists over ct=0,1)

    #pragma unroll 1
    for (int ct = 0; ct < 4; ++ct) {
        const int n0 = ct * 128;
        f32x4 acc[2][4] = {};
        #pragma unroll 1
        for (int kc = 0; kc < 4; ++kc) {
            #pragma unroll
            for (int is = 0; is < 4; ++is)
                async16(Bt + (size_t)(n0 + srow0 + is * 8) * 256 + kc * 64 + swb,
                        lB + is * 512);
            __syncthreads();
            #pragma unroll
            for (int kk = 0; kk < 2; ++kk) {
                const int sa = (kc * 8 + kk * 4 + quad) ^ (frow & 7);
                const int sb = (kk * 4 + quad) ^ (frow & 7);
                bf16x8 af[2], bf[4];
                #pragma unroll
                for (int i = 0; i < 2; ++i)
                    af[i] = *(const bf16x8*)(As + (wm * 32 + i * 16 + frow) * 256 + sa * 8);
                #pragma unroll
                for (int j = 0; j < 4; ++j)
                    bf[j] = *(const bf16x8*)(Bs + (wn * 64 + j * 16 + frow) * 64 + sb * 8);
                #pragma unroll
                for (int i = 0; i < 2; ++i)
                    #pragma unroll
                    for (int j = 0; j < 4; ++j)
                        acc[i][j] = __builtin_amdgcn_mfma_f32_16x16x32_bf16(
                            bf[j], af[i], acc[i][j], 0, 0, 0);   // SWAPPED
            }
            __syncthreads();
        }

        if (ct < 2) {
            // ---- fused alpha: relu(acc) is an A-fragment (row=frow=node,
            // k-slot(quad,e)=col per wfragT's permutation); 2 j-pairs -> K=32.
            #pragma unroll
            for (int p = 0; p < 2; ++p) {
                bf16x8 wf = *(const bf16x8*)(
                    wfragT + (((ct << 2) + (wn << 1) + p) * 64 + lane) * 8);
                #pragma unroll
                for (int i = 0; i < 2; ++i) {
                    f32x4 v0 = acc[i][2 * p], v1 = acc[i][2 * p + 1];
                    unsigned u0 = cvt_pk(fmaxf(v0[0], 0.f), fmaxf(v0[1], 0.f));
                    unsigned u1 = cvt_pk(fmaxf(v0[2], 0.f), fmaxf(v0[3], 0.f));
                    unsigned u2 = cvt_pk(fmaxf(v1[0], 0.f), fmaxf(v1[1], 0.f));
                    unsigned u3 = cvt_pk(fmaxf(v1[2], 0.f), fmaxf(v1[3], 0.f));
                    union { unsigned u[4]; bf16x8 b; } a8 = {{u0, u1, u2, u3}};
                    aacc[i] = __builtin_amdgcn_mfma_f32_16x16x32_bf16(
                        a8.b, wf, aacc[i], 0, 0, 0);
                }
            }
            if (ct == 1) {
                // finalize alpha: fold hi+lo residual, reduce across wn
                // halves through redA, write global.
                #pragma unroll
                for (int i = 0; i < 2; ++i)
                    #pragma unroll
                    for (int r = 0; r < 4; ++r)
                        aacc[i][r] += __shfl_xor(aacc[i][r], 8);
                if (wn == 0 && frow < 8) {
                    #pragma unroll
                    for (int i = 0; i < 2; ++i)
                        #pragma unroll
                        for (int r = 0; r < 4; ++r)
                            redA[(wm * 32 + i * 16 + quad * 4 + r) * 8 + frow] = aacc[i][r];
                }
                __syncthreads();
                if (wn == 1 && frow < 8) {
                    #pragma unroll
                    for (int i = 0; i < 2; ++i)
                        #pragma unroll
                        for (int r = 0; r < 4; ++r) {
                            int ml = wm * 32 + i * 16 + quad * 4 + r;
                            size_t m = m0 + ml;
                            if (m < NN)
                                alpha[m * 8 + frow] = redA[ml * 8 + frow] + aacc[i][r];
                        }
                }
            }
        } else {
            // ---- h_n epilogue: bias (vector add along reg axis), relu,
            // pack 4 bf16 -> one 8B store per (i,j).
            #pragma unroll
            for (int j = 0; j < 4; ++j) {
                f32x4 bv = *(const f32x4*)(bn1 + (ct - 2) * 128 + wn * 64 + j * 16 + quad * 4);
                #pragma unroll
                for (int i = 0; i < 2; ++i) {
                    f32x4 v = acc[i][j] + bv;
                    unsigned u0 = cvt_pk(fmaxf(v[0], 0.f), fmaxf(v[1], 0.f));
                    unsigned u1 = cvt_pk(fmaxf(v[2], 0.f), fmaxf(v[3], 0.f));
                    uint2 w; w.x = u0; w.y = u1;
                    size_t row = m0 + wm * 32 + i * 16 + frow;
                    *(uint2*)(C + row * 256 + (ct - 2) * 128 + wn * 64 + j * 16 + quad * 4) = w;
                }
            }
        }
    }
}

// ---------- kernel 3: softmax + gated segment-sum + tiny GEMV ----------
__device__ __forceinline__ int lower_bound(const int* __restrict__ b, int key) {
    int lo = 0, hi = NN;
    while (lo < hi) { int mid = (lo + hi) >> 1; if (b[mid] < key) lo = mid + 1; else hi = mid; }
    return lo;
}

__global__ __launch_bounds__(256) void pool2(
    const float* __restrict__ alpha, const unsigned short* __restrict__ h,
    const float* __restrict__ Wn2, const float* __restrict__ bn2,
    const int* __restrict__ batch, float* __restrict__ out) {
    __shared__ float red[256];
    __shared__ float mh[8], ih[8];
    __shared__ float gate_s[64][8];   // 2 KB
    __shared__ float Gs[256 * 8];     // 8 KB
    const int g = blockIdx.x, t = threadIdx.x;
    const int start = lower_bound(batch, g);
    const int end   = lower_bound(batch, g + 1);
    const int hd = t & 7;

    float mloc = -INFINITY;
    for (int n = start + (t >> 3); n < end; n += 32)
        mloc = fmaxf(mloc, alpha[n * 8 + hd]);
    red[t] = mloc; __syncthreads();
    for (int off = 128; off >= 8; off >>= 1) {
        if (t < off) red[t] = fmaxf(red[t], red[t + off]);
        __syncthreads();
    }
    if (t < 8) mh[t] = red[t];
    __syncthreads();
    const float mm = mh[hd];

    float sloc = 0.f;
    for (int n = start + (t >> 3); n < end; n += 32)
        sloc += __expf(alpha[n * 8 + hd] - mm);
    red[t] = sloc; __syncthreads();
    for (int off = 128; off >= 8; off >>= 1) {
        if (t < off) red[t] += red[t + off];
        __syncthreads();
    }
    if (t < 8) ih[t] = 1.0f / (red[t] + 1e-16f);
    __syncthreads();

    // pass 3: G[k, 0..7] += gate[n,:] * h_n[n, k]
    // 2 node-groups of 128 threads; each thread owns cols {2tc, 2tc+1}
    // via one 4B ushort2 load per node (2x node ILP, half the load instrs).
    const int half = t >> 7;          // node group
    const int tc   = t & 127;         // column-pair index
    f32x2 a0[4] = {}, a1[4] = {};     // col 2tc / 2tc+1, head pairs
    for (int c0 = start; c0 < end; c0 += 64) {
        const int cn = min(64, end - c0);
        __syncthreads();
        for (int u = t; u < cn * 8; u += 256)
            gate_s[u >> 3][u & 7] =
                __expf(alpha[(c0 + (u >> 3)) * 8 + (u & 7)] - mh[u & 7]) * ih[u & 7];
        __syncthreads();
        const int jend = half ? cn : min(cn, 32);
        for (int j = half * 32; j < jend; ++j) {
            unsigned hv = *(const unsigned*)(h + (size_t)(c0 + j) * 256 + tc * 2);
            float h0 = b2f((unsigned short)(hv & 0xFFFFu));
            float h1 = b2f((unsigned short)(hv >> 16));
            f32x2 h20 = {h0, h0}, h21 = {h1, h1};
            const f32x2* gp = (const f32x2*)&gate_s[j][0];   // LDS broadcast
            #pragma unroll
            for (int i = 0; i < 4; ++i) {
                f32x2 g2 = gp[i];
                a0[i] += g2 * h20;
                a1[i] += g2 * h21;
            }
        }
    }
    __syncthreads();
    if (half == 0) {
        #pragma unroll
        for (int i = 0; i < 4; ++i) {
            *(f32x2*)&Gs[(2 * tc) * 8 + 2 * i]     = a0[i];
            *(f32x2*)&Gs[(2 * tc + 1) * 8 + 2 * i] = a1[i];
        }
    }
    __syncthreads();
    if (half == 1) {
        #pragma unroll
        for (int i = 0; i < 4; ++i) {
            *(f32x2*)&Gs[(2 * tc) * 8 + 2 * i]     += a0[i];
            *(f32x2*)&Gs[(2 * tc + 1) * 8 + 2 * i] += a1[i];
        }
    }
    __syncthreads();

    float acc = 0.f;
    #pragma unroll 4
    for (int k = 0; k < 256; ++k)
        acc += Gs[k * 8 + hd] * Wn2[k * 256 + t];
    const float sg = (end > start) ? 1.0f : 0.0f;
    out[g * 256 + t] = acc + sg * bn2[t];
}

// ---------- launch ----------
extern "C" void kernel_launch(void* const* d_in, const int* in_sizes, int n_in,
                              void* d_out, int out_size, void* d_ws, size_t ws_size,
                              hipStream_t stream) {
    const float* x     = (const float*)d_in[0];
    const int*   batch = (const int*)d_in[1];
    const float* Wg1   = (const float*)d_in[2];
    const float* Wg2   = (const float*)d_in[3];
    const float* Wn1   = (const float*)d_in[4];
    const float* bn1   = (const float*)d_in[5];
    const float* Wn2   = (const float*)d_in[6];
    const float* bn2   = (const float*)d_in[7];
    float* out = (float*)d_out;

    unsigned short* h      = (unsigned short*)d_ws;           // MPAD*256 (h_n only)
    unsigned short* wcatT  = h + (size_t)MPAD * 256;          // 512*256
    unsigned short* wfragT = wcatT + 512 * 256;               // 8*64*8
    float* alpha = (float*)(wfragT + 4096);                   // NN*8

    convert_w<<<528, 256, 0, stream>>>(Wg1, Wn1, Wg2, wcatT, wfragT);
    gemm_fused<<<3126, 256, 0, stream>>>(x, wcatT, bn1, wfragT, h, alpha);
    pool2<<<NGRAPH, 256, 0, stream>>>(alpha, h, Wn2, bn2, batch, out);
}

// Round 5
// 426.763 us; speedup vs baseline: 1.1508x; 1.0281x over previous
//
#include <hip/hip_runtime.h>

#define NN     200000
#define MPAD   200064   // 3126 * 64
#define NGRAPH 1024

typedef __bf16 bf16x8 __attribute__((ext_vector_type(8)));
typedef float  f32x4  __attribute__((ext_vector_type(4)));
typedef float  f32x2  __attribute__((ext_vector_type(2)));

// ---------- helpers ----------
__device__ __forceinline__ unsigned short f2bu(float f) {
    unsigned u = __float_as_uint(f);
    unsigned r = (u + 0x7FFFu + ((u >> 16) & 1u)) >> 16;
    return (unsigned short)r;
}
__device__ __forceinline__ float b2f(unsigned short u) {
    return __uint_as_float(((unsigned)u) << 16);
}
__device__ __forceinline__ unsigned cvt_pk(float lo, float hi) {
    // RNE, bit-identical to f2bu for finite inputs
    unsigned r;
    asm("v_cvt_pk_bf16_f32 %0, %1, %2" : "=v"(r) : "v"(lo), "v"(hi));
    return r;
}
__device__ __forceinline__ void async16(const void* g, void* l) {
    __builtin_amdgcn_global_load_lds(
        (const __attribute__((address_space(1))) void*)g,
        (__attribute__((address_space(3))) void*)l, 16, 0, 0);
}

// ---------- kernel 1: weight prep ----------
// wcatT[n][k] = [Wg1|Wn1][k][n] bf16.
// wfragT: 8 slices x 64 lanes x 8 bf16 — B-fragments for the fused alpha
// MFMA (see gemm_fused). hi rows + lo-residual rows = fp32-accurate Wg2.
__global__ __launch_bounds__(256) void convert_w(
    const float* __restrict__ Wg1, const float* __restrict__ Wn1,
    const float* __restrict__ Wg2,
    unsigned short* __restrict__ wcatT, unsigned short* __restrict__ wfragT) {
    int i = blockIdx.x * 256 + threadIdx.x;
    if (i < 512 * 256) {
        int n = i >> 8, k = i & 255;
        float v = (n < 256) ? Wg1[k * 256 + n] : Wn1[k * 256 + (n - 256)];
        wcatT[i] = f2bu(v);
    } else if (i < 512 * 256 + 4096) {
        int j = i - 512 * 256;
        int e = j & 7, l = (j >> 3) & 63, s = j >> 9;
        int quad = l >> 4, c = l & 15;
        int n = (s >> 2) * 128 + ((s >> 1) & 1) * 64 + (s & 1) * 32
              + ((e >> 2) * 16) + quad * 4 + (e & 3);
        float w = Wg2[n * 8 + (c & 7)];
        unsigned short hi = f2bu(w);
        wfragT[j] = (c < 8) ? hi : f2bu(w - b2f(hi));
    }
}

// ---------- kernel 2: fused GEMM + alpha ----------
// h_n = relu(x@Wn1 + bn1)  -> C [MPAD,256] bf16   (col-tiles ct=2,3)
// alpha = relu(x@Wg1)@Wg2  -> alpha [NN,8] f32    (col-tiles ct=0,1, fused)
// Round-5 change: 2-phase double-buffered B staging (T3-minimal). Staging
// unit = 32 k-columns (8 KB) = one kk-step; stage(u+1) is issued BEFORE
// compute(u), so the barrier's vmcnt drain waits on loads issued a full
// compute phase (~8 MFMA) earlier — rounds 2-4 issued loads with ZERO
// prefetch distance and exposed the whole L2 latency 16x per block.
// LDS: As 32K + Bs 2x8K + redA 2K = 50 KB -> 3 blocks/CU (unchanged).
__global__ __launch_bounds__(256, 3) void gemm_fused(
    const float* __restrict__ x,              // [NN,256] f32
    const unsigned short* __restrict__ Bt,    // wcatT [512,256] bf16
    const float* __restrict__ bn1,            // [256]
    const unsigned short* __restrict__ wfragT,// [8*64*8] bf16
    unsigned short* __restrict__ C,           // h_n [MPAD,256] bf16
    float* __restrict__ alpha) {              // [NN,8] f32
    __shared__ unsigned short As[64 * 256];   // 32 KB
    __shared__ unsigned short Bs[2][128 * 32];// 2 x 8 KB (128 n x 32 k)
    __shared__ float redA[64 * 8];            // 2 KB (alpha cross-wave red)
    const int tid  = threadIdx.x;
    const int lane = tid & 63;
    const int wave = tid >> 6;
    const int wm = wave >> 1, wn = wave & 1;
    const size_t m0 = (size_t)blockIdx.x * 64;
    const int frow = lane & 15;
    const int quad = lane >> 4;

    // ---- B staging pattern: unit u covers n=[ (u>>3)*128, +128 ),
    // k=[ (u&7)*32, +32 ). LDS layout [row][slot], slot swizzled by
    // quad ^ ((row>>1)&3); gload_lds writes linearly so the swizzle is
    // applied on the per-lane GLOBAL source address.
    const int srow = wave * 32 + (lane >> 2);      // row (inst 0)
    const int koff = (((lane & 3) ^ ((srow >> 1) & 3)) << 3);

    // ---- stage A panel (64 rows): f32 x -> bf16, chunk c -> slot c^(r&7)
    {
        const int lane4 = lane * 4;
        const int c = lane4 >> 3;
        #pragma unroll 1
        for (int p2 = 0; p2 < 2; ++p2) {
            float4 v[8];
            #pragma unroll
            for (int q = 0; q < 8; ++q) {
                int row = (p2 * 8 + q) * 4 + wave;
                size_t gr = m0 + row;
                if (gr > (size_t)(NN - 1)) gr = NN - 1;   // clamp pad rows
                v[q] = *(const float4*)(x + gr * 256 + lane4);
            }
            #pragma unroll
            for (int q = 0; q < 8; ++q) {
                int row = (p2 * 8 + q) * 4 + wave;
                unsigned u0 = cvt_pk(v[q].x, v[q].y);
                unsigned u1 = cvt_pk(v[q].z, v[q].w);
                int off = row * 256 + ((c ^ (row & 7)) << 3) + (lane4 & 7);
                uint2 w; w.x = u0; w.y = u1;
                *(uint2*)(As + off) = w;          // 8B, aligned
            }
        }
    }
    // prologue: stage unit 0 into buf0
    {
        const unsigned short* src = Bt + (size_t)srow * 256 + koff;
        async16(src, &Bs[0][wave * 1024]);
        async16(src + 16 * 256, &Bs[0][wave * 1024 + 512]);
    }
    __syncthreads();   // drains A ds_writes + stage(0)

    f32x4 aacc[2] = {};   // alpha accumulator (persists over ct=0,1)

    #pragma unroll 1
    for (int ct = 0; ct < 4; ++ct) {
        f32x4 acc[2][4] = {};
        #pragma unroll 2
        for (int k8 = 0; k8 < 8; ++k8) {
            const int u = ct * 8 + k8;
            if (u + 1 < 32) {              // stage next unit (prefetch)
                const int nu = u + 1;
                const unsigned short* src = Bt
                    + (size_t)((nu >> 3) * 128 + srow) * 256 + (nu & 7) * 32 + koff;
                unsigned short* dst = &Bs[nu & 1][wave * 1024];
                async16(src, dst);
                async16(src + 16 * 256, dst + 512);
            }
            const unsigned short* bb = &Bs[u & 1][0];
            const int sa = (k8 * 4 + quad) ^ (frow & 7);
            const int bslot = quad ^ ((frow >> 1) & 3);
            bf16x8 af[2], bf[4];
            #pragma unroll
            for (int i = 0; i < 2; ++i)
                af[i] = *(const bf16x8*)(As + (wm * 32 + i * 16 + frow) * 256 + sa * 8);
            #pragma unroll
            for (int j = 0; j < 4; ++j)
                bf[j] = *(const bf16x8*)(bb + (wn * 64 + j * 16 + frow) * 32 + bslot * 8);
            #pragma unroll
            for (int i = 0; i < 2; ++i)
                #pragma unroll
                for (int j = 0; j < 4; ++j)
                    acc[i][j] = __builtin_amdgcn_mfma_f32_16x16x32_bf16(
                        bf[j], af[i], acc[i][j], 0, 0, 0);   // SWAPPED operands
            __syncthreads();   // stage(u+1) landed; buf[u&1] free for u+2
        }

        if (ct < 2) {
            // ---- fused alpha: relu(acc) is an A-fragment (row=frow=node,
            // k-slot(quad,e)=col per wfragT's permutation); 2 j-pairs -> K=32.
            #pragma unroll
            for (int p = 0; p < 2; ++p) {
                bf16x8 wf = *(const bf16x8*)(
                    wfragT + (((ct << 2) + (wn << 1) + p) * 64 + lane) * 8);
                #pragma unroll
                for (int i = 0; i < 2; ++i) {
                    f32x4 v0 = acc[i][2 * p], v1 = acc[i][2 * p + 1];
                    unsigned u0 = cvt_pk(fmaxf(v0[0], 0.f), fmaxf(v0[1], 0.f));
                    unsigned u1 = cvt_pk(fmaxf(v0[2], 0.f), fmaxf(v0[3], 0.f));
                    unsigned u2 = cvt_pk(fmaxf(v1[0], 0.f), fmaxf(v1[1], 0.f));
                    unsigned u3 = cvt_pk(fmaxf(v1[2], 0.f), fmaxf(v1[3], 0.f));
                    union { unsigned u[4]; bf16x8 b; } a8 = {{u0, u1, u2, u3}};
                    aacc[i] = __builtin_amdgcn_mfma_f32_16x16x32_bf16(
                        a8.b, wf, aacc[i], 0, 0, 0);
                }
            }
            if (ct == 1) {
                // finalize alpha: fold hi+lo residual, reduce across wn
                // halves through redA, write global.
                #pragma unroll
                for (int i = 0; i < 2; ++i)
                    #pragma unroll
                    for (int r = 0; r < 4; ++r)
                        aacc[i][r] += __shfl_xor(aacc[i][r], 8);
                if (wn == 0 && frow < 8) {
                    #pragma unroll
                    for (int i = 0; i < 2; ++i)
                        #pragma unroll
                        for (int r = 0; r < 4; ++r)
                            redA[(wm * 32 + i * 16 + quad * 4 + r) * 8 + frow] = aacc[i][r];
                }
                __syncthreads();
                if (wn == 1 && frow < 8) {
                    #pragma unroll
                    for (int i = 0; i < 2; ++i)
                        #pragma unroll
                        for (int r = 0; r < 4; ++r) {
                            int ml = wm * 32 + i * 16 + quad * 4 + r;
                            size_t m = m0 + ml;
                            if (m < NN)
                                alpha[m * 8 + frow] = redA[ml * 8 + frow] + aacc[i][r];
                        }
                }
            }
        } else {
            // ---- h_n epilogue: bias (vector add along reg axis), relu,
            // pack 4 bf16 -> one 8B store per (i,j).
            #pragma unroll
            for (int j = 0; j < 4; ++j) {
                f32x4 bv = *(const f32x4*)(bn1 + (ct - 2) * 128 + wn * 64 + j * 16 + quad * 4);
                #pragma unroll
                for (int i = 0; i < 2; ++i) {
                    f32x4 v = acc[i][j] + bv;
                    unsigned u0 = cvt_pk(fmaxf(v[0], 0.f), fmaxf(v[1], 0.f));
                    unsigned u1 = cvt_pk(fmaxf(v[2], 0.f), fmaxf(v[3], 0.f));
                    uint2 w; w.x = u0; w.y = u1;
                    size_t row = m0 + wm * 32 + i * 16 + frow;
                    *(uint2*)(C + row * 256 + (ct - 2) * 128 + wn * 64 + j * 16 + quad * 4) = w;
                }
            }
        }
    }
}

// ---------- kernel 3: softmax + gated segment-sum + tiny GEMV ----------
__device__ __forceinline__ int lower_bound(const int* __restrict__ b, int key) {
    int lo = 0, hi = NN;
    while (lo < hi) { int mid = (lo + hi) >> 1; if (b[mid] < key) lo = mid + 1; else hi = mid; }
    return lo;
}

#define GST 9   // padded head-stride for G partials (bank-conflict-free)

__global__ __launch_bounds__(256) void pool2(
    const float* __restrict__ alpha, const unsigned short* __restrict__ h,
    const float* __restrict__ Wn2, const float* __restrict__ bn2,
    const int* __restrict__ batch, float* __restrict__ out) {
    __shared__ float red[256];
    __shared__ float mh[8], ih[8];
    __shared__ float gate_s[64][8];       // 2 KB (zero-padded past cn)
    __shared__ float Gs4[4][256 * GST];   // 36 KB group partials
    const int g = blockIdx.x, t = threadIdx.x;
    const int start = lower_bound(batch, g);
    const int end   = lower_bound(batch, g + 1);
    const int hd = t & 7;

    float mloc = -INFINITY;
    for (int n = start + (t >> 3); n < end; n += 32)
        mloc = fmaxf(mloc, alpha[n * 8 + hd]);
    red[t] = mloc; __syncthreads();
    for (int off = 128; off >= 8; off >>= 1) {
        if (t < off) red[t] = fmaxf(red[t], red[t + off]);
        __syncthreads();
    }
    if (t < 8) mh[t] = red[t];
    __syncthreads();
    const float mm = mh[hd];

    float sloc = 0.f;
    for (int n = start + (t >> 3); n < end; n += 32)
        sloc += __expf(alpha[n * 8 + hd] - mm);
    red[t] = sloc; __syncthreads();
    for (int off = 128; off >= 8; off >>= 1) {
        if (t < off) red[t] += red[t + off];
        __syncthreads();
    }
    if (t < 8) ih[t] = 1.0f / (red[t] + 1e-16f);
    __syncthreads();

    // pass 3: G[k, 0..7] += gate[n,:] * h_n[n, k]
    // 4 node-groups x 64 threads; thread owns cols c4..c4+3 via one 8B
    // ushort4 load per node. Gate rows zero-padded so the j-loop trip
    // count is a static 16 (#pragma unroll 4 -> loads pipelined).
    const int grp = t >> 6;
    const int c4  = (t & 63) * 4;
    f32x2 G[4][4] = {};                   // [col d][head pair i]
    for (int c0 = start; c0 < end; c0 += 64) {
        const int cn = min(64, end - c0);
        __syncthreads();
        #pragma unroll
        for (int u2 = 0; u2 < 2; ++u2) {
            int u = t + u2 * 256;
            int j = u >> 3, hh = u & 7;
            gate_s[j][hh] = (j < cn)
                ? __expf(alpha[(size_t)(c0 + j) * 8 + hh] - mh[hh]) * ih[hh]
                : 0.0f;
        }
        __syncthreads();
        const int j0 = grp * 16;
        #pragma unroll 4
        for (int jj = 0; jj < 16; ++jj) {
            const int j = j0 + jj;
            // c0+j < NN+64 <= MPAD: pad rows hold finite data, gate=0
            ushort4 hv = *(const ushort4*)(h + (size_t)(c0 + j) * 256 + c4);
            const f32x2* gp = (const f32x2*)&gate_s[j][0];   // LDS broadcast
            const f32x2 g0 = gp[0], g1 = gp[1], g2 = gp[2], g3 = gp[3];
            f32x2 v;
            v = {b2f(hv.x), b2f(hv.x)};
            G[0][0] += g0 * v; G[0][1] += g1 * v; G[0][2] += g2 * v; G[0][3] += g3 * v;
            v = {b2f(hv.y), b2f(hv.y)};
            G[1][0] += g0 * v; G[1][1] += g1 * v; G[1][2] += g2 * v; G[1][3] += g3 * v;
            v = {b2f(hv.z), b2f(hv.z)};
            G[2][0] += g0 * v; G[2][1] += g1 * v; G[2][2] += g2 * v; G[2][3] += g3 * v;
            v = {b2f(hv.w), b2f(hv.w)};
            G[3][0] += g0 * v; G[3][1] += g1 * v; G[3][2] += g2 * v; G[3][3] += g3 * v;
        }
    }
    __syncthreads();
    // write group partials (once per block; GST=9 spreads banks)
    #pragma unroll
    for (int d = 0; d < 4; ++d)
        #pragma unroll
        for (int i = 0; i < 4; ++i) {
            Gs4[grp][(c4 + d) * GST + 2 * i]     = G[d][i][0];
            Gs4[grp][(c4 + d) * GST + 2 * i + 1] = G[d][i][1];
        }
    __syncthreads();
    // reduce 4 groups -> Gs4[0]; thread t owns row k=t (9t%32 bijective)
    {
        float* Gf = &Gs4[0][0];
        #pragma unroll
        for (int e = 0; e < 8; ++e) {
            int idx = t * GST + e;
            Gf[idx] = Gf[idx] + Gf[256 * GST + idx]
                    + Gf[512 * GST + idx] + Gf[768 * GST + idx];
        }
    }
    __syncthreads();

    float acc = 0.f;
    #pragma unroll 4
    for (int k = 0; k < 256; ++k)
        acc += Gs4[0][k * GST + hd] * Wn2[k * 256 + t];
    const float sg = (end > start) ? 1.0f : 0.0f;
    out[g * 256 + t] = acc + sg * bn2[t];
}

// ---------- launch ----------
extern "C" void kernel_launch(void* const* d_in, const int* in_sizes, int n_in,
                              void* d_out, int out_size, void* d_ws, size_t ws_size,
                              hipStream_t stream) {
    const float* x     = (const float*)d_in[0];
    const int*   batch = (const int*)d_in[1];
    const float* Wg1   = (const float*)d_in[2];
    const float* Wg2   = (const float*)d_in[3];
    const float* Wn1   = (const float*)d_in[4];
    const float* bn1   = (const float*)d_in[5];
    const float* Wn2   = (const float*)d_in[6];
    const float* bn2   = (const float*)d_in[7];
    float* out = (float*)d_out;

    unsigned short* h      = (unsigned short*)d_ws;           // MPAD*256 (h_n only)
    unsigned short* wcatT  = h + (size_t)MPAD * 256;          // 512*256
    unsigned short* wfragT = wcatT + 512 * 256;               // 8*64*8
    float* alpha = (float*)(wfragT + 4096);                   // NN*8

    convert_w<<<528, 256, 0, stream>>>(Wg1, Wn1, Wg2, wcatT, wfragT);
    gemm_fused<<<3126, 256, 0, stream>>>(x, wcatT, bn1, wfragT, h, alpha);
    pool2<<<NGRAPH, 256, 0, stream>>>(alpha, h, Wn2, bn2, batch, out);
}